// Round 4
// baseline (652.520 us; speedup 1.0000x reference)
//
#include <hip/hip_runtime.h>
#include <hip/hip_bf16.h>

typedef unsigned short u16;
typedef __bf16 bf16x8 __attribute__((ext_vector_type(8)));
typedef float f32x4 __attribute__((ext_vector_type(4)));
typedef __attribute__((address_space(1))) void* gp1_t;
typedef __attribute__((address_space(3))) void* lp3_t;

#define D_IN   4096
#define D_OUT  4096
#define M_ROWS 8192   // B*S = 4*2048

// ---- workspace layout (bytes) ----
#define OFF_NORMS  0u          // 4096 f32 (atomic-accumulated; memset to 0 first)
#define OFF_QVALS  16384u      // 4 f32: v[204],v[205],v[3890],v[3891]
#define OFF_XB     573696u     // 8192*4096 bf16 (67108864 B)
#define OFF_WB     67682560u   // 4096*4096 bf16 (33554432 B)

static __device__ __forceinline__ u16 f2bf(float f) {
    __hip_bfloat16 h = __float2bfloat16(f);
    u16 u; __builtin_memcpy(&u, &h, 2);
    return u;
}

// K1: blocks 0..511 -> column-norm partials (atomicAdd into norms);
//     blocks 512..33279 -> cast x to bf16 (float4 per thread).
__global__ __launch_bounds__(256) void k1_cast_colnorm(const float* __restrict__ x,
                                                       const float* __restrict__ W,
                                                       u16* __restrict__ xb,
                                                       float* __restrict__ norms) {
    const int b = blockIdx.x;
    if (b < 512) {
        const int j  = (b & 15) * 256 + threadIdx.x;
        const int r0 = (b >> 4) * 128;
        float s = 0.f;
        #pragma unroll 4
        for (int r = 0; r < 128; ++r) s += fabsf(W[(size_t)(r0 + r) * D_IN + j]);
        atomicAdd(&norms[j], s);
    } else {
        const size_t i4 = (size_t)(b - 512) * 256 + threadIdx.x;
        const float4 v = ((const float4*)x)[i4];
        ushort4 r;
        r.x = f2bf(v.x); r.y = f2bf(v.y); r.z = f2bf(v.z); r.w = f2bf(v.w);
        ((ushort4*)xb)[i4] = r;
    }
}

// K2: stable-rank order statistics: grid 16, block 256.
__global__ void rank_select(const float* __restrict__ norms, float* __restrict__ qvals) {
    __shared__ float sn[D_IN];
    const int tid = threadIdx.x;
    for (int i = tid; i < D_IN; i += 256) sn[i] = norms[i];
    __syncthreads();
    const int j = blockIdx.x * 256 + tid;
    const float vj = sn[j];
    int r = 0;
    #pragma unroll 8
    for (int i = 0; i < D_IN; ++i) {
        const float vi = sn[i];
        r += (vi < vj) || (vi == vj && i < j);
    }
    if      (r == 204)  qvals[0] = vj;
    else if (r == 205)  qvals[1] = vj;
    else if (r == 3890) qvals[2] = vj;
    else if (r == 3891) qvals[3] = vj;
}

// K3: one block per output row: mask, n_bin, masked row abs-mean, rescale + bf16 cast.
__global__ __launch_bounds__(256) void k3_scale_wbin(const float* __restrict__ W,
                                                     const float* __restrict__ norms,
                                                     const float* __restrict__ qvals,
                                                     u16* __restrict__ wb) {
    __shared__ float red[8];
    const int o = blockIdx.x, t = threadIdx.x;
    const int wave = t >> 6, lane = t & 63;
    const float lower = qvals[0] + 0.75f * (qvals[1] - qvals[0]);
    const float upper = qvals[2] + 0.25f * (qvals[3] - qvals[2]);
    const float4* row4 = (const float4*)(W + (size_t)o * D_IN);
    const float4* n4   = (const float4*)norms;

    float4 wv[4];
    int binbits[4];
    float cnt = 0.f, sum = 0.f;
    #pragma unroll
    for (int it = 0; it < 4; ++it) {
        const int c = it * 256 + t;
        wv[it] = row4[c];
        const float4 nv = n4[c];
        const bool b0 = !(nv.x > lower && nv.x < upper);
        const bool b1 = !(nv.y > lower && nv.y < upper);
        const bool b2 = !(nv.z > lower && nv.z < upper);
        const bool b3 = !(nv.w > lower && nv.w < upper);
        binbits[it] = (b0 ? 1 : 0) | (b1 ? 2 : 0) | (b2 ? 4 : 0) | (b3 ? 8 : 0);
        cnt += (float)(b0 + b1 + b2 + b3);
        sum += (b0 ? fabsf(wv[it].x) : 0.f) + (b1 ? fabsf(wv[it].y) : 0.f)
             + (b2 ? fabsf(wv[it].z) : 0.f) + (b3 ? fabsf(wv[it].w) : 0.f);
    }
    #pragma unroll
    for (int off = 32; off > 0; off >>= 1) {
        cnt += __shfl_down(cnt, off, 64);
        sum += __shfl_down(sum, off, 64);
    }
    if (lane == 0) { red[wave] = cnt; red[4 + wave] = sum; }
    __syncthreads();
    const float nbin = red[0] + red[1] + red[2] + red[3];
    const float ssum = red[4] + red[5] + red[6] + red[7];
    const float sc = ssum / nbin;

    ushort4* out = (ushort4*)(wb + (size_t)o * D_IN);
    #pragma unroll
    for (int it = 0; it < 4; ++it) {
        const int c = it * 256 + t;
        const int bb = binbits[it];
        ushort4 r;
        r.x = f2bf((bb & 1) ? wv[it].x * sc : wv[it].x);
        r.y = f2bf((bb & 2) ? wv[it].y * sc : wv[it].y);
        r.z = f2bf((bb & 4) ? wv[it].z * sc : wv[it].z);
        r.w = f2bf((bb & 8) ? wv[it].w * sc : wv[it].w);
        out[c] = r;
    }
}

// ============================================================================
// K4: 256x256-tile 8-phase GEMM, BK=64, 8 waves (2M x 4N), counted vmcnt,
//     register-double-buffered fragments (prefetch next phase's ds_reads under
//     the current phase's MFMA cluster).
//
// Delta vs the PASSING R1 kernel is ONLY the fragment prefetch:
//  - staging addressing is R1's (runtime byte offset on the global pointer,
//    builtin offset arg = 0 — the non-zero literal offset arg is the R2
//    suspect and is reverted);
//  - uniform 32-iteration loop with clamped junk stages (R1's tail), no peel.
//
// Phase p: STAGE -> [vmcnt(4) on p3/p7] -> BAR -> lgkmcnt(0) (waits the
// prefetch issued at phase p-1; ~free) -> setprio(1) -> prefetch phase p+1's
// frags (4 A-reads; +4 B-reads on odd p) -> 16 MFMA -> BAR.
//
// RAW: p3's vmcnt(4) retires prev-p6/p7 (1,0) + p0/p1 (1,1); p7's vmcnt(4)
//      retires p2..p5 = (0,0),(0,1) -> every prefetch-read is covered.
// WAR: restage of a slot is >=2 phases after its last prefetch-read; a read
//      issued at phase q completes at q+1's lgkmcnt(0), before any wave can
//      cross q+1's closing BAR and issue q+2's stage.
// Last iteration: junk stages (clamped t=63) are written but never consumed;
// p7's final prefetch loads junk into regs that are discarded; final
// vmcnt(0) drains in-flight LDS-DMA before teardown.
// ============================================================================

#define BAR() do { asm volatile("" ::: "memory"); __builtin_amdgcn_s_barrier(); \
                   asm volatile("" ::: "memory"); } while (0)

#define LDA(buf, kh, mf) \
    (*(const bf16x8*)(smA + (buf)*32768 + (kh)*16384 + wr*8192 + (mf)*1024 + lane_rd))
#define LDB(buf, kh, nf) \
    (*(const bf16x8*)(smB + (buf)*32768 + (kh)*16384 + wc*4096 + (nf)*1024 + lane_rd))

#define STAGE_A(buf, kh, OFFV) do { \
    char* l_ = smA + (buf)*32768 + (kh)*16384 + wofs; \
    __builtin_amdgcn_global_load_lds((gp1_t)(srcA0 + (OFFV)), (lp3_t)l_, 16, 0, 0); \
    __builtin_amdgcn_global_load_lds((gp1_t)(srcA1 + (OFFV)), (lp3_t)(l_ + 8192), 16, 0, 0); \
} while (0)

#define STAGE_B(buf, kh, OFFV) do { \
    char* l_ = smB + (buf)*32768 + (kh)*16384 + wofs; \
    __builtin_amdgcn_global_load_lds((gp1_t)(srcB0 + (OFFV)), (lp3_t)l_, 16, 0, 0); \
    __builtin_amdgcn_global_load_lds((gp1_t)(srcB1 + (OFFV)), (lp3_t)(l_ + 8192), 16, 0, 0); \
} while (0)

#define NOST ((void)0)

#define PF_A(R0,R1,R2,R3, buf, kh, mg) do { \
    R0 = LDA(buf, kh, (mg)*4 + 0); R1 = LDA(buf, kh, (mg)*4 + 1); \
    R2 = LDA(buf, kh, (mg)*4 + 2); R3 = LDA(buf, kh, (mg)*4 + 3); \
} while (0)

#define PF_B(R0,R1,R2,R3, buf, kh) do { \
    R0 = LDB(buf, kh, 0); R1 = LDB(buf, kh, 1); \
    R2 = LDB(buf, kh, 2); R3 = LDB(buf, kh, 3); \
} while (0)

#define PF_NONE ((void)0)

#define MFMA __builtin_amdgcn_mfma_f32_16x16x32_bf16

// VM: 0 = none, 1 = vmcnt(4)
#define PHASE(mg, A0_,A1_,A2_,A3_, B0_,B1_,B2_,B3_, VM, ST, PFA, PFB) do { \
    ST; \
    if ((VM) == 1) { asm volatile("s_waitcnt vmcnt(4)" ::: "memory"); } \
    BAR(); \
    asm volatile("s_waitcnt lgkmcnt(0)" ::: "memory"); \
    __builtin_amdgcn_sched_barrier(0); \
    __builtin_amdgcn_s_setprio(1); \
    PFA; \
    PFB; \
    __builtin_amdgcn_sched_barrier(0); \
    acc[(mg)*4+0][0] = MFMA(A0_, B0_, acc[(mg)*4+0][0], 0, 0, 0); \
    acc[(mg)*4+0][1] = MFMA(A0_, B1_, acc[(mg)*4+0][1], 0, 0, 0); \
    acc[(mg)*4+0][2] = MFMA(A0_, B2_, acc[(mg)*4+0][2], 0, 0, 0); \
    acc[(mg)*4+0][3] = MFMA(A0_, B3_, acc[(mg)*4+0][3], 0, 0, 0); \
    acc[(mg)*4+1][0] = MFMA(A1_, B0_, acc[(mg)*4+1][0], 0, 0, 0); \
    acc[(mg)*4+1][1] = MFMA(A1_, B1_, acc[(mg)*4+1][1], 0, 0, 0); \
    acc[(mg)*4+1][2] = MFMA(A1_, B2_, acc[(mg)*4+1][2], 0, 0, 0); \
    acc[(mg)*4+1][3] = MFMA(A1_, B3_, acc[(mg)*4+1][3], 0, 0, 0); \
    acc[(mg)*4+2][0] = MFMA(A2_, B0_, acc[(mg)*4+2][0], 0, 0, 0); \
    acc[(mg)*4+2][1] = MFMA(A2_, B1_, acc[(mg)*4+2][1], 0, 0, 0); \
    acc[(mg)*4+2][2] = MFMA(A2_, B2_, acc[(mg)*4+2][2], 0, 0, 0); \
    acc[(mg)*4+2][3] = MFMA(A2_, B3_, acc[(mg)*4+2][3], 0, 0, 0); \
    acc[(mg)*4+3][0] = MFMA(A3_, B0_, acc[(mg)*4+3][0], 0, 0, 0); \
    acc[(mg)*4+3][1] = MFMA(A3_, B1_, acc[(mg)*4+3][1], 0, 0, 0); \
    acc[(mg)*4+3][2] = MFMA(A3_, B2_, acc[(mg)*4+3][2], 0, 0, 0); \
    acc[(mg)*4+3][3] = MFMA(A3_, B3_, acc[(mg)*4+3][3], 0, 0, 0); \
    __builtin_amdgcn_s_setprio(0); \
    BAR(); \
} while (0)

__global__ __launch_bounds__(512, 2) void gemm8(const u16* __restrict__ A, const u16* __restrict__ B,
                                                const float* __restrict__ bias, float* __restrict__ C) {
    __shared__ u16 sA[2][2][256 * 32];   // 64 KiB
    __shared__ u16 sB[2][2][256 * 32];   // 64 KiB
    char* const smA = (char*)&sA[0][0][0];
    char* const smB = (char*)&sB[0][0][0];

    const int tid  = threadIdx.x;
    const int wave = tid >> 6, lane = tid & 63;
    const int wr = wave >> 2, wc = wave & 3;        // 2M x 4N wave grid
    const int r15 = lane & 15, q = lane >> 4;
    const int wofs = wave * 1024;

    // XCD-aware bijective swizzle (512 blocks % 8 == 0)
    const int swz = ((int)blockIdx.x & 7) * 64 + ((int)blockIdx.x >> 3);
    const int by = swz >> 4, bx = swz & 15;
    const int m0 = by * 256, n0 = bx * 256;

    // reader: phys-in-slot = wr*8192(or wc*4096) + mf*1024 + lane_rd
    const int lane_rd = (r15 * 64 + q * 16) ^ (((r15 >> 1) & 7) << 4);

    // writer: per-lane inverse-swizzled global source for the 2 loads/slot
    const int P0  = wofs + lane * 16;
    const int xv  = ((lane >> 3) & 7) << 4;
    const int lb0 = P0 ^ xv;
    const int lb1 = (P0 + 8192) ^ xv;
    const char* const gA = (const char*)(A + (size_t)m0 * D_IN);
    const char* const gB = (const char*)(B + (size_t)n0 * D_IN);
    const char* const srcA0 = gA + (size_t)(lb0 >> 6) * (D_IN * 2) + (lb0 & 63);
    const char* const srcA1 = gA + (size_t)(lb1 >> 6) * (D_IN * 2) + (lb1 & 63);
    const char* const srcB0 = gB + (size_t)(lb0 >> 6) * (D_IN * 2) + (lb0 & 63);
    const char* const srcB1 = gB + (size_t)(lb1 >> 6) * (D_IN * 2) + (lb1 & 63);

    f32x4 acc[8][4] = {};
    bf16x8 aX0{}, aX1{}, aX2{}, aX3{}, aY0{}, aY1{}, aY2{}, aY3{};
    bf16x8 b00{}, b01{}, b02{}, b03{}, b10{}, b11{}, b12{}, b13{};

    // prologue: stage tile0 (buf0, both khalves) + tile1 khalf0 (buf1)
    STAGE_A(0, 0, 0);   STAGE_B(0, 0, 0);
    STAGE_A(0, 1, 64);  STAGE_B(0, 1, 64);
    STAGE_A(1, 0, 128); STAGE_B(1, 0, 128);
    asm volatile("s_waitcnt vmcnt(4)" ::: "memory");   // tile0 landed
    BAR();
    // initial fragment prefetch for phase 0
    PF_A(aX0, aX1, aX2, aX3, 0, 0, 0);
    PF_B(b00, b01, b02, b03, 0, 0);

    #pragma unroll 1
    for (int i = 0; i < 32; ++i) {                     // 64 K-tiles, 2 per iter
        const int t2  = (2 * i + 2 > 63) ? 63 : 2 * i + 2;  // clamped junk stages on
        const int t3  = (2 * i + 3 > 63) ? 63 : 2 * i + 3;  // last iter, never read
        const int o11 = i * 256 + 192;   // tile 2i+1, kh1 (always real)
        const int o00 = t2 * 128;        // tile t2,  kh0
        const int o01 = o00 + 64;        // tile t2,  kh1
        const int o10 = t3 * 128;        // tile t3,  kh0
        PHASE(0, aX0,aX1,aX2,aX3, b00,b01,b02,b03, 0, STAGE_A(1,1,o11), PF_A(aY0,aY1,aY2,aY3, 0,0,1), PF_NONE);
        PHASE(1, aY0,aY1,aY2,aY3, b00,b01,b02,b03, 0, STAGE_B(1,1,o11), PF_A(aX0,aX1,aX2,aX3, 0,1,0), PF_B(b10,b11,b12,b13, 0,1));
        PHASE(0, aX0,aX1,aX2,aX3, b10,b11,b12,b13, 0, STAGE_A(0,0,o00), PF_A(aY0,aY1,aY2,aY3, 0,1,1), PF_NONE);
        PHASE(1, aY0,aY1,aY2,aY3, b10,b11,b12,b13, 1, STAGE_B(0,0,o00), PF_A(aX0,aX1,aX2,aX3, 1,0,0), PF_B(b00,b01,b02,b03, 1,0));
        PHASE(0, aX0,aX1,aX2,aX3, b00,b01,b02,b03, 0, STAGE_A(0,1,o01), PF_A(aY0,aY1,aY2,aY3, 1,0,1), PF_NONE);
        PHASE(1, aY0,aY1,aY2,aY3, b00,b01,b02,b03, 0, STAGE_B(0,1,o01), PF_A(aX0,aX1,aX2,aX3, 1,1,0), PF_B(b10,b11,b12,b13, 1,1));
        PHASE(0, aX0,aX1,aX2,aX3, b10,b11,b12,b13, 0, STAGE_A(1,0,o10), PF_A(aY0,aY1,aY2,aY3, 1,1,1), PF_NONE);
        PHASE(1, aY0,aY1,aY2,aY3, b10,b11,b12,b13, 1, STAGE_B(1,0,o10), PF_A(aX0,aX1,aX2,aX3, 0,0,0), PF_B(b00,b01,b02,b03, 0,0));
    }

    // epilogue: C/D layout col = lane&15 (n), row = (lane>>4)*4 + reg (m)
    const int cm = q * 4;
    #pragma unroll
    for (int nf = 0; nf < 4; ++nf) {
        const int n = n0 + wc * 64 + nf * 16 + r15;
        const float bv = bias[n];
        #pragma unroll
        for (int mf = 0; mf < 8; ++mf) {
            const int mbase = m0 + wr * 128 + mf * 16 + cm;
            #pragma unroll
            for (int rr = 0; rr < 4; ++rr)
                C[(size_t)(mbase + rr) * D_OUT + n] = acc[mf][nf][rr] + bv;
        }
    }
    // drain any in-flight LDS-DMA (junk stages) before workgroup teardown
    asm volatile("s_waitcnt vmcnt(0)" ::: "memory");
}

extern "C" void kernel_launch(void* const* d_in, const int* in_sizes, int n_in,
                              void* d_out, int out_size, void* d_ws, size_t ws_size,
                              hipStream_t stream) {
    const float* x    = (const float*)d_in[0];   // [8192, 4096]
    const float* W    = (const float*)d_in[1];   // [4096, 4096]
    const float* bias = (const float*)d_in[2];   // [4096]
    float* out = (float*)d_out;                  // [8192, 4096]

    char* ws = (char*)d_ws;
    float* norms = (float*)(ws + OFF_NORMS);
    float* qvals = (float*)(ws + OFF_QVALS);
    u16*   xb    = (u16*)(ws + OFF_XB);
    u16*   wb    = (u16*)(ws + OFF_WB);

    hipMemsetAsync(norms, 0, D_IN * sizeof(float), stream);
    k1_cast_colnorm<<<512 + 32768, 256, 0, stream>>>(x, W, xb, norms);
    rank_select<<<16, 256, 0, stream>>>(norms, qvals);
    k3_scale_wbin<<<4096, 256, 0, stream>>>(W, norms, qvals, wb);
    gemm8<<<dim3(512), dim3(512), 0, stream>>>(xb, wb, bias, out);
}

// Round 5
// 631.141 us; speedup vs baseline: 1.0339x; 1.0339x over previous
//
#include <hip/hip_runtime.h>
#include <hip/hip_bf16.h>

typedef unsigned short u16;
typedef __bf16 bf16x8 __attribute__((ext_vector_type(8)));
typedef float f32x4 __attribute__((ext_vector_type(4)));
typedef __attribute__((address_space(1))) void* gp1_t;
typedef __attribute__((address_space(3))) void* lp3_t;

#define D_IN   4096
#define D_OUT  4096
#define M_ROWS 8192   // B*S = 4*2048

// ---- workspace layout (bytes) ----
#define OFF_NORMS  0u          // 4096 f32 (atomic-accumulated; memset to 0 first)
#define OFF_QVALS  16384u      // 4 f32: v[204],v[205],v[3890],v[3891]
#define OFF_XB     573696u     // 8192*4096 bf16 (67108864 B)
#define OFF_WB     67682560u   // 4096*4096 bf16 (33554432 B)

static __device__ __forceinline__ u16 f2bf(float f) {
    __hip_bfloat16 h = __float2bfloat16(f);
    u16 u; __builtin_memcpy(&u, &h, 2);
    return u;
}

// K1: blocks 0..511 -> column-norm partials (atomicAdd into norms);
//     blocks 512..33279 -> cast x to bf16 (float4 per thread).
__global__ __launch_bounds__(256) void k1_cast_colnorm(const float* __restrict__ x,
                                                       const float* __restrict__ W,
                                                       u16* __restrict__ xb,
                                                       float* __restrict__ norms) {
    const int b = blockIdx.x;
    if (b < 512) {
        const int j  = (b & 15) * 256 + threadIdx.x;
        const int r0 = (b >> 4) * 128;
        float s = 0.f;
        #pragma unroll 4
        for (int r = 0; r < 128; ++r) s += fabsf(W[(size_t)(r0 + r) * D_IN + j]);
        atomicAdd(&norms[j], s);
    } else {
        const size_t i4 = (size_t)(b - 512) * 256 + threadIdx.x;
        const float4 v = ((const float4*)x)[i4];
        ushort4 r;
        r.x = f2bf(v.x); r.y = f2bf(v.y); r.z = f2bf(v.z); r.w = f2bf(v.w);
        ((ushort4*)xb)[i4] = r;
    }
}

// K2: stable-rank order statistics: grid 16, block 256.
__global__ void rank_select(const float* __restrict__ norms, float* __restrict__ qvals) {
    __shared__ float sn[D_IN];
    const int tid = threadIdx.x;
    for (int i = tid; i < D_IN; i += 256) sn[i] = norms[i];
    __syncthreads();
    const int j = blockIdx.x * 256 + tid;
    const float vj = sn[j];
    int r = 0;
    #pragma unroll 8
    for (int i = 0; i < D_IN; ++i) {
        const float vi = sn[i];
        r += (vi < vj) || (vi == vj && i < j);
    }
    if      (r == 204)  qvals[0] = vj;
    else if (r == 205)  qvals[1] = vj;
    else if (r == 3890) qvals[2] = vj;
    else if (r == 3891) qvals[3] = vj;
}

// K3: one block per output row: mask, n_bin, masked row abs-mean, rescale + bf16 cast.
__global__ __launch_bounds__(256) void k3_scale_wbin(const float* __restrict__ W,
                                                     const float* __restrict__ norms,
                                                     const float* __restrict__ qvals,
                                                     u16* __restrict__ wb) {
    __shared__ float red[8];
    const int o = blockIdx.x, t = threadIdx.x;
    const int wave = t >> 6, lane = t & 63;
    const float lower = qvals[0] + 0.75f * (qvals[1] - qvals[0]);
    const float upper = qvals[2] + 0.25f * (qvals[3] - qvals[2]);
    const float4* row4 = (const float4*)(W + (size_t)o * D_IN);
    const float4* n4   = (const float4*)norms;

    float4 wv[4];
    int binbits[4];
    float cnt = 0.f, sum = 0.f;
    #pragma unroll
    for (int it = 0; it < 4; ++it) {
        const int c = it * 256 + t;
        wv[it] = row4[c];
        const float4 nv = n4[c];
        const bool b0 = !(nv.x > lower && nv.x < upper);
        const bool b1 = !(nv.y > lower && nv.y < upper);
        const bool b2 = !(nv.z > lower && nv.z < upper);
        const bool b3 = !(nv.w > lower && nv.w < upper);
        binbits[it] = (b0 ? 1 : 0) | (b1 ? 2 : 0) | (b2 ? 4 : 0) | (b3 ? 8 : 0);
        cnt += (float)(b0 + b1 + b2 + b3);
        sum += (b0 ? fabsf(wv[it].x) : 0.f) + (b1 ? fabsf(wv[it].y) : 0.f)
             + (b2 ? fabsf(wv[it].z) : 0.f) + (b3 ? fabsf(wv[it].w) : 0.f);
    }
    #pragma unroll
    for (int off = 32; off > 0; off >>= 1) {
        cnt += __shfl_down(cnt, off, 64);
        sum += __shfl_down(sum, off, 64);
    }
    if (lane == 0) { red[wave] = cnt; red[4 + wave] = sum; }
    __syncthreads();
    const float nbin = red[0] + red[1] + red[2] + red[3];
    const float ssum = red[4] + red[5] + red[6] + red[7];
    const float sc = ssum / nbin;

    ushort4* out = (ushort4*)(wb + (size_t)o * D_IN);
    #pragma unroll
    for (int it = 0; it < 4; ++it) {
        const int c = it * 256 + t;
        const int bb = binbits[it];
        ushort4 r;
        r.x = f2bf((bb & 1) ? wv[it].x * sc : wv[it].x);
        r.y = f2bf((bb & 2) ? wv[it].y * sc : wv[it].y);
        r.z = f2bf((bb & 4) ? wv[it].z * sc : wv[it].z);
        r.w = f2bf((bb & 8) ? wv[it].w * sc : wv[it].w);
        out[c] = r;
    }
}

// ============================================================================
// K4: 256x256-tile 8-phase GEMM, BK=64, 8 waves (2M x 4N), counted vmcnt,
//     register-double-buffered fragments.
//
// Delta vs the PASSING R4 kernel is ONLY scheduling freedom:
//  - removed the 2x sched_barrier(0) pins and the explicit lgkmcnt(0) per
//    phase. Plain-C ds_reads get compiler-managed counted lgkmcnt waits
//    (m97 r109) and may interleave with the MFMA cluster; MFMAs can begin
//    issuing at the top of the phase instead of after the full read burst.
//
// Ordering that still holds:
//  RAW (stage->read): vmcnt(4)+BAR before any read of a freshly staged slot
//    (p3 covers prev-p6/p7 (1,0) + p0/p1 (1,1); p7 covers p2..p5 (0,0),(0,1));
//    the memory-clobber asm around s_barrier keeps ds_reads/stages from
//    being moved across barriers by the compiler.
//  WAR (read->restage): a slot's restage is >=2 phases after its last read;
//    the read's consuming MFMA (compiler-waited) is >=3 barriers before the
//    restaging DMA can land.
//  Last iteration: clamped junk stages written but never consumed; final
//    vmcnt(0) drains in-flight LDS-DMA before teardown.
// ============================================================================

#define BAR() do { asm volatile("" ::: "memory"); __builtin_amdgcn_s_barrier(); \
                   asm volatile("" ::: "memory"); } while (0)

#define LDA(buf, kh, mf) \
    (*(const bf16x8*)(smA + (buf)*32768 + (kh)*16384 + wr*8192 + (mf)*1024 + lane_rd))
#define LDB(buf, kh, nf) \
    (*(const bf16x8*)(smB + (buf)*32768 + (kh)*16384 + wc*4096 + (nf)*1024 + lane_rd))

#define STAGE_A(buf, kh, OFFV) do { \
    char* l_ = smA + (buf)*32768 + (kh)*16384 + wofs; \
    __builtin_amdgcn_global_load_lds((gp1_t)(srcA0 + (OFFV)), (lp3_t)l_, 16, 0, 0); \
    __builtin_amdgcn_global_load_lds((gp1_t)(srcA1 + (OFFV)), (lp3_t)(l_ + 8192), 16, 0, 0); \
} while (0)

#define STAGE_B(buf, kh, OFFV) do { \
    char* l_ = smB + (buf)*32768 + (kh)*16384 + wofs; \
    __builtin_amdgcn_global_load_lds((gp1_t)(srcB0 + (OFFV)), (lp3_t)l_, 16, 0, 0); \
    __builtin_amdgcn_global_load_lds((gp1_t)(srcB1 + (OFFV)), (lp3_t)(l_ + 8192), 16, 0, 0); \
} while (0)

#define NOST ((void)0)

#define PF_A(R0,R1,R2,R3, buf, kh, mg) do { \
    R0 = LDA(buf, kh, (mg)*4 + 0); R1 = LDA(buf, kh, (mg)*4 + 1); \
    R2 = LDA(buf, kh, (mg)*4 + 2); R3 = LDA(buf, kh, (mg)*4 + 3); \
} while (0)

#define PF_B(R0,R1,R2,R3, buf, kh) do { \
    R0 = LDB(buf, kh, 0); R1 = LDB(buf, kh, 1); \
    R2 = LDB(buf, kh, 2); R3 = LDB(buf, kh, 3); \
} while (0)

#define PF_NONE ((void)0)

#define MFMA __builtin_amdgcn_mfma_f32_16x16x32_bf16

// VM: 0 = none, 1 = vmcnt(4)
#define PHASE(mg, A0_,A1_,A2_,A3_, B0_,B1_,B2_,B3_, VM, ST, PFA, PFB) do { \
    ST; \
    if ((VM) == 1) { asm volatile("s_waitcnt vmcnt(4)" ::: "memory"); } \
    BAR(); \
    __builtin_amdgcn_s_setprio(1); \
    PFA; \
    PFB; \
    acc[(mg)*4+0][0] = MFMA(A0_, B0_, acc[(mg)*4+0][0], 0, 0, 0); \
    acc[(mg)*4+0][1] = MFMA(A0_, B1_, acc[(mg)*4+0][1], 0, 0, 0); \
    acc[(mg)*4+0][2] = MFMA(A0_, B2_, acc[(mg)*4+0][2], 0, 0, 0); \
    acc[(mg)*4+0][3] = MFMA(A0_, B3_, acc[(mg)*4+0][3], 0, 0, 0); \
    acc[(mg)*4+1][0] = MFMA(A1_, B0_, acc[(mg)*4+1][0], 0, 0, 0); \
    acc[(mg)*4+1][1] = MFMA(A1_, B1_, acc[(mg)*4+1][1], 0, 0, 0); \
    acc[(mg)*4+1][2] = MFMA(A1_, B2_, acc[(mg)*4+1][2], 0, 0, 0); \
    acc[(mg)*4+1][3] = MFMA(A1_, B3_, acc[(mg)*4+1][3], 0, 0, 0); \
    acc[(mg)*4+2][0] = MFMA(A2_, B0_, acc[(mg)*4+2][0], 0, 0, 0); \
    acc[(mg)*4+2][1] = MFMA(A2_, B1_, acc[(mg)*4+2][1], 0, 0, 0); \
    acc[(mg)*4+2][2] = MFMA(A2_, B2_, acc[(mg)*4+2][2], 0, 0, 0); \
    acc[(mg)*4+2][3] = MFMA(A2_, B3_, acc[(mg)*4+2][3], 0, 0, 0); \
    acc[(mg)*4+3][0] = MFMA(A3_, B0_, acc[(mg)*4+3][0], 0, 0, 0); \
    acc[(mg)*4+3][1] = MFMA(A3_, B1_, acc[(mg)*4+3][1], 0, 0, 0); \
    acc[(mg)*4+3][2] = MFMA(A3_, B2_, acc[(mg)*4+3][2], 0, 0, 0); \
    acc[(mg)*4+3][3] = MFMA(A3_, B3_, acc[(mg)*4+3][3], 0, 0, 0); \
    __builtin_amdgcn_s_setprio(0); \
    BAR(); \
} while (0)

__global__ __launch_bounds__(512, 2) void gemm8(const u16* __restrict__ A, const u16* __restrict__ B,
                                                const float* __restrict__ bias, float* __restrict__ C) {
    __shared__ u16 sA[2][2][256 * 32];   // 64 KiB
    __shared__ u16 sB[2][2][256 * 32];   // 64 KiB
    char* const smA = (char*)&sA[0][0][0];
    char* const smB = (char*)&sB[0][0][0];

    const int tid  = threadIdx.x;
    const int wave = tid >> 6, lane = tid & 63;
    const int wr = wave >> 2, wc = wave & 3;        // 2M x 4N wave grid
    const int r15 = lane & 15, q = lane >> 4;
    const int wofs = wave * 1024;

    // XCD-aware bijective swizzle (512 blocks % 8 == 0)
    const int swz = ((int)blockIdx.x & 7) * 64 + ((int)blockIdx.x >> 3);
    const int by = swz >> 4, bx = swz & 15;
    const int m0 = by * 256, n0 = bx * 256;

    // reader: phys-in-slot = wr*8192(or wc*4096) + mf*1024 + lane_rd
    const int lane_rd = (r15 * 64 + q * 16) ^ (((r15 >> 1) & 7) << 4);

    // writer: per-lane inverse-swizzled global source for the 2 loads/slot
    const int P0  = wofs + lane * 16;
    const int xv  = ((lane >> 3) & 7) << 4;
    const int lb0 = P0 ^ xv;
    const int lb1 = (P0 + 8192) ^ xv;
    const char* const gA = (const char*)(A + (size_t)m0 * D_IN);
    const char* const gB = (const char*)(B + (size_t)n0 * D_IN);
    const char* const srcA0 = gA + (size_t)(lb0 >> 6) * (D_IN * 2) + (lb0 & 63);
    const char* const srcA1 = gA + (size_t)(lb1 >> 6) * (D_IN * 2) + (lb1 & 63);
    const char* const srcB0 = gB + (size_t)(lb0 >> 6) * (D_IN * 2) + (lb0 & 63);
    const char* const srcB1 = gB + (size_t)(lb1 >> 6) * (D_IN * 2) + (lb1 & 63);

    f32x4 acc[8][4] = {};
    bf16x8 aX0{}, aX1{}, aX2{}, aX3{}, aY0{}, aY1{}, aY2{}, aY3{};
    bf16x8 b00{}, b01{}, b02{}, b03{}, b10{}, b11{}, b12{}, b13{};

    // prologue: stage tile0 (buf0, both khalves) + tile1 khalf0 (buf1)
    STAGE_A(0, 0, 0);   STAGE_B(0, 0, 0);
    STAGE_A(0, 1, 64);  STAGE_B(0, 1, 64);
    STAGE_A(1, 0, 128); STAGE_B(1, 0, 128);
    asm volatile("s_waitcnt vmcnt(4)" ::: "memory");   // tile0 landed
    BAR();
    // initial fragment prefetch for phase 0
    PF_A(aX0, aX1, aX2, aX3, 0, 0, 0);
    PF_B(b00, b01, b02, b03, 0, 0);

    #pragma unroll 1
    for (int i = 0; i < 32; ++i) {                     // 64 K-tiles, 2 per iter
        const int t2  = (2 * i + 2 > 63) ? 63 : 2 * i + 2;  // clamped junk stages on
        const int t3  = (2 * i + 3 > 63) ? 63 : 2 * i + 3;  // last iter, never read
        const int o11 = i * 256 + 192;   // tile 2i+1, kh1 (always real)
        const int o00 = t2 * 128;        // tile t2,  kh0
        const int o01 = o00 + 64;        // tile t2,  kh1
        const int o10 = t3 * 128;        // tile t3,  kh0
        PHASE(0, aX0,aX1,aX2,aX3, b00,b01,b02,b03, 0, STAGE_A(1,1,o11), PF_A(aY0,aY1,aY2,aY3, 0,0,1), PF_NONE);
        PHASE(1, aY0,aY1,aY2,aY3, b00,b01,b02,b03, 0, STAGE_B(1,1,o11), PF_A(aX0,aX1,aX2,aX3, 0,1,0), PF_B(b10,b11,b12,b13, 0,1));
        PHASE(0, aX0,aX1,aX2,aX3, b10,b11,b12,b13, 0, STAGE_A(0,0,o00), PF_A(aY0,aY1,aY2,aY3, 0,1,1), PF_NONE);
        PHASE(1, aY0,aY1,aY2,aY3, b10,b11,b12,b13, 1, STAGE_B(0,0,o00), PF_A(aX0,aX1,aX2,aX3, 1,0,0), PF_B(b00,b01,b02,b03, 1,0));
        PHASE(0, aX0,aX1,aX2,aX3, b00,b01,b02,b03, 0, STAGE_A(0,1,o01), PF_A(aY0,aY1,aY2,aY3, 1,0,1), PF_NONE);
        PHASE(1, aY0,aY1,aY2,aY3, b00,b01,b02,b03, 0, STAGE_B(0,1,o01), PF_A(aX0,aX1,aX2,aX3, 1,1,0), PF_B(b10,b11,b12,b13, 1,1));
        PHASE(0, aX0,aX1,aX2,aX3, b10,b11,b12,b13, 0, STAGE_A(1,0,o10), PF_A(aY0,aY1,aY2,aY3, 1,1,1), PF_NONE);
        PHASE(1, aY0,aY1,aY2,aY3, b10,b11,b12,b13, 1, STAGE_B(1,0,o10), PF_A(aX0,aX1,aX2,aX3, 0,0,0), PF_B(b00,b01,b02,b03, 0,0));
    }

    // epilogue: C/D layout col = lane&15 (n), row = (lane>>4)*4 + reg (m)
    const int cm = q * 4;
    #pragma unroll
    for (int nf = 0; nf < 4; ++nf) {
        const int n = n0 + wc * 64 + nf * 16 + r15;
        const float bv = bias[n];
        #pragma unroll
        for (int mf = 0; mf < 8; ++mf) {
            const int mbase = m0 + wr * 128 + mf * 16 + cm;
            #pragma unroll
            for (int rr = 0; rr < 4; ++rr)
                C[(size_t)(mbase + rr) * D_OUT + n] = acc[mf][nf][rr] + bv;
        }
    }
    // drain any in-flight LDS-DMA (junk stages) before workgroup teardown
    asm volatile("s_waitcnt vmcnt(0)" ::: "memory");
}

extern "C" void kernel_launch(void* const* d_in, const int* in_sizes, int n_in,
                              void* d_out, int out_size, void* d_ws, size_t ws_size,
                              hipStream_t stream) {
    const float* x    = (const float*)d_in[0];   // [8192, 4096]
    const float* W    = (const float*)d_in[1];   // [4096, 4096]
    const float* bias = (const float*)d_in[2];   // [4096]
    float* out = (float*)d_out;                  // [8192, 4096]

    char* ws = (char*)d_ws;
    float* norms = (float*)(ws + OFF_NORMS);
    float* qvals = (float*)(ws + OFF_QVALS);
    u16*   xb    = (u16*)(ws + OFF_XB);
    u16*   wb    = (u16*)(ws + OFF_WB);

    hipMemsetAsync(norms, 0, D_IN * sizeof(float), stream);
    k1_cast_colnorm<<<512 + 32768, 256, 0, stream>>>(x, W, xb, norms);
    rank_select<<<16, 256, 0, stream>>>(norms, qvals);
    k3_scale_wbin<<<4096, 256, 0, stream>>>(W, norms, qvals, wb);
    gemm8<<<dim3(512), dim3(512), 0, stream>>>(xb, wb, bias, out);
}